// Round 1
// baseline (10975.776 us; speedup 1.0000x reference)
//
#include <hip/hip_runtime.h>
#include <cstdint>

#define NNODES 20000
#define NEDGES 320000
#define ETOT   340000   // NEDGES + NNODES self loops
#define TSTEPS 10
#define BCLF   4096
#define EMB    128
#define HC     512      // HEADS * EMB
#define NEG_SLOPE 0.2f

// ---------------- CSR build (once for all 10 graphs) ----------------
__global__ void count_kernel(const int* __restrict__ edges, int* __restrict__ counts) {
    int e = blockIdx.x * 256 + threadIdx.x;
    int g = blockIdx.y;
    if (e >= ETOT) return;
    int d = (e < NEDGES) ? edges[(g * 2 + 1) * NEDGES + e] : (e - NEDGES);
    atomicAdd(&counts[g * NNODES + d], 1);
}

__global__ void scan_kernel(const int* __restrict__ counts, int* __restrict__ rowptr,
                            int* __restrict__ cursor) {
    int g = blockIdx.x;
    __shared__ int buf[256];
    __shared__ int carry_s;
    if (threadIdx.x == 0) carry_s = 0;
    __syncthreads();
    const int* c = counts + g * NNODES;
    int* rp = rowptr + g * (NNODES + 1);
    int* cu = cursor + g * NNODES;
    for (int base = 0; base < NNODES; base += 256) {
        int i = base + threadIdx.x;
        int v = (i < NNODES) ? c[i] : 0;
        buf[threadIdx.x] = v;
        __syncthreads();
        for (int off = 1; off < 256; off <<= 1) {
            int t = (threadIdx.x >= off) ? buf[threadIdx.x - off] : 0;
            __syncthreads();
            buf[threadIdx.x] += t;
            __syncthreads();
        }
        int excl = carry_s + buf[threadIdx.x] - v;
        if (i < NNODES) { rp[i] = excl; cu[i] = excl; }
        int tot = buf[255];
        __syncthreads();
        if (threadIdx.x == 0) carry_s += tot;
        __syncthreads();
    }
    if (threadIdx.x == 0) rp[NNODES] = carry_s;
}

__global__ void fill_kernel(const int* __restrict__ edges, int* __restrict__ cursor,
                            int* __restrict__ csr_src, int* __restrict__ csr_eid) {
    int e = blockIdx.x * 256 + threadIdx.x;
    int g = blockIdx.y;
    if (e >= ETOT) return;
    int s, d;
    if (e < NEDGES) { s = edges[(g * 2) * NEDGES + e]; d = edges[(g * 2 + 1) * NEDGES + e]; }
    else           { s = e - NEDGES; d = s; }
    int pos = atomicAdd(&cursor[g * NNODES + d], 1);
    csr_src[(long)g * ETOT + pos] = s;
    csr_eid[(long)g * ETOT + pos] = e;
}

// ---------------- generic register-tiled fp32 GEMM: C = op(A @ B^T + bias) ----------------
// A: [M,K] row-major, B: [N,K] row-major (weights are [out,in]). blockIdx.z picks branch
// pointers. Block = 16x16 threads; tile BM x BN; each thread TM x TN (BM = 16*TM).
// Assumes K % 16 == 0, N % BN == 0 for stores (true for all uses: N in {512,128}).
template <int BM, int BN, int TM, int TN, bool RELU, bool BIAS>
__global__ __launch_bounds__(256) void gemm_tn(
    const float* __restrict__ A0, const float* __restrict__ A1,
    const float* __restrict__ B0, const float* __restrict__ B1,
    const float* __restrict__ bias0, const float* __restrict__ bias1,
    float* __restrict__ C, long cStride, int M, int N, int K) {
    const int z = blockIdx.z;
    const float* __restrict__ A = z ? A1 : A0;
    const float* __restrict__ B = z ? B1 : B0;
    const float* __restrict__ bias = z ? bias1 : bias0;
    float* __restrict__ Cz = C + (long)z * cStride;

    __shared__ float As[16][BM + 4];
    __shared__ float Bs[16][BN + 4];

    const int tx = threadIdx.x, ty = threadIdx.y;
    const int tid = ty * 16 + tx;
    const int row0 = blockIdx.x * BM;
    const int col0 = blockIdx.y * BN;

    float acc[TM][TN];
#pragma unroll
    for (int i = 0; i < TM; i++)
#pragma unroll
        for (int j = 0; j < TN; j++) acc[i][j] = 0.f;

    for (int k0 = 0; k0 < K; k0 += 16) {
        __syncthreads();
#pragma unroll
        for (int ld = tid * 4; ld < BM * 16; ld += 1024) {
            int r = ld >> 4, kk = ld & 15;
            int ar = row0 + r;
            float4 v = (ar < M) ? *(const float4*)&A[(long)ar * K + k0 + kk]
                                : make_float4(0.f, 0.f, 0.f, 0.f);
            As[kk + 0][r] = v.x; As[kk + 1][r] = v.y; As[kk + 2][r] = v.z; As[kk + 3][r] = v.w;
        }
#pragma unroll
        for (int ld = tid * 4; ld < BN * 16; ld += 1024) {
            int r = ld >> 4, kk = ld & 15;
            int bc = col0 + r;
            float4 v = (bc < N) ? *(const float4*)&B[(long)bc * K + k0 + kk]
                                : make_float4(0.f, 0.f, 0.f, 0.f);
            Bs[kk + 0][r] = v.x; Bs[kk + 1][r] = v.y; Bs[kk + 2][r] = v.z; Bs[kk + 3][r] = v.w;
        }
        __syncthreads();
#pragma unroll
        for (int kk = 0; kk < 16; kk++) {
            float a[TM], b[TN];
#pragma unroll
            for (int i = 0; i < TM; i += 4) *(float4*)&a[i] = *(const float4*)&As[kk][ty * TM + i];
#pragma unroll
            for (int j = 0; j < TN; j += 4) *(float4*)&b[j] = *(const float4*)&Bs[kk][tx * TN + j];
#pragma unroll
            for (int i = 0; i < TM; i++)
#pragma unroll
                for (int j = 0; j < TN; j++) acc[i][j] = fmaf(a[i], b[j], acc[i][j]);
        }
    }

#pragma unroll
    for (int i = 0; i < TM; i++) {
        int row = row0 + ty * TM + i;
        if (row >= M) continue;
#pragma unroll
        for (int j0 = 0; j0 < TN; j0 += 4) {
            int col = col0 + tx * TN + j0;
            float4 v = make_float4(acc[i][j0 + 0], acc[i][j0 + 1], acc[i][j0 + 2], acc[i][j0 + 3]);
            if (BIAS) {
                v.x += bias[col + 0]; v.y += bias[col + 1];
                v.z += bias[col + 2]; v.w += bias[col + 3];
            }
            if (RELU) {
                v.x = fmaxf(v.x, 0.f); v.y = fmaxf(v.y, 0.f);
                v.z = fmaxf(v.z, 0.f); v.w = fmaxf(v.w, 0.f);
            }
            *(float4*)&Cz[(long)row * N + col] = v;
        }
    }
}

// ---------------- per-node attention scores + den zeroing ----------------
// one wave per (branch, node); lane covers 8 contiguous channels of the 512
__global__ __launch_bounds__(256) void scores_kernel(
    const float* __restrict__ H,
    const float* __restrict__ as0, const float* __restrict__ as1,
    const float* __restrict__ ad0, const float* __restrict__ ad1,
    float* __restrict__ s_src, float* __restrict__ s_dst, float* __restrict__ den) {
    int z = blockIdx.y;
    int n = blockIdx.x * 4 + (threadIdx.x >> 6);
    int lane = threadIdx.x & 63;
    if (n >= NNODES) return;
    const float* as = z ? as1 : as0;
    const float* ad = z ? ad1 : ad0;
    const float* hrow = H + ((long)z * NNODES + n) * HC + lane * 8;
    float4 h0 = *(const float4*)hrow;
    float4 h1 = *(const float4*)(hrow + 4);
    float4 a0 = *(const float4*)&as[lane * 8];
    float4 a1 = *(const float4*)&as[lane * 8 + 4];
    float4 d0 = *(const float4*)&ad[lane * 8];
    float4 d1 = *(const float4*)&ad[lane * 8 + 4];
    float ps = h0.x * a0.x + h0.y * a0.y + h0.z * a0.z + h0.w * a0.w +
               h1.x * a1.x + h1.y * a1.y + h1.z * a1.z + h1.w * a1.w;
    float pd = h0.x * d0.x + h0.y * d0.y + h0.z * d0.z + h0.w * d0.w +
               h1.x * d1.x + h1.y * d1.y + h1.z * d1.z + h1.w * d1.w;
    for (int off = 8; off; off >>= 1) {
        ps += __shfl_down(ps, off, 16);
        pd += __shfl_down(pd, off, 16);
    }
    if ((lane & 15) == 0) {
        int head = lane >> 4;
        long idx = ((long)z * NNODES + n) * 4 + head;
        s_src[idx] = ps;
        s_dst[idx] = pd;
        den[idx] = 0.f;
    }
}

// ---------------- per-edge softmax numerator + denominator accumulation ----------------
// softmax max-subtraction skipped: logits are O(1) (invariant result)
__global__ void edge_kernel(const int* __restrict__ edges,
                            const float* __restrict__ s_src, const float* __restrict__ s_dst,
                            float* __restrict__ ex, float* __restrict__ den, int g) {
    int e = blockIdx.x * 256 + threadIdx.x;
    if (e >= ETOT) return;
    int z = blockIdx.y;
    int s, d;
    if (e < NEDGES) { s = edges[(g * 2) * NEDGES + e]; d = edges[(g * 2 + 1) * NEDGES + e]; }
    else           { s = e - NEDGES; d = s; }
    float4 vs = *(const float4*)&s_src[((long)z * NNODES + s) * 4];
    float4 vd = *(const float4*)&s_dst[((long)z * NNODES + d) * 4];
    float l0 = vs.x + vd.x, l1 = vs.y + vd.y, l2 = vs.z + vd.z, l3 = vs.w + vd.w;
    l0 = (l0 >= 0.f) ? l0 : NEG_SLOPE * l0;
    l1 = (l1 >= 0.f) ? l1 : NEG_SLOPE * l1;
    l2 = (l2 >= 0.f) ? l2 : NEG_SLOPE * l2;
    l3 = (l3 >= 0.f) ? l3 : NEG_SLOPE * l3;
    float4 exv = make_float4(expf(l0), expf(l1), expf(l2), expf(l3));
    *(float4*)&ex[((long)z * ETOT + e) * 4] = exv;
    float* dp = &den[((long)z * NNODES + d) * 4];
    atomicAdd(dp + 0, exv.x);
    atomicAdd(dp + 1, exv.y);
    atomicAdd(dp + 2, exv.z);
    atomicAdd(dp + 3, exv.w);
}

// ---------------- CSR aggregation: OUT[n] = (1/den) * sum_e ex[e]*H[src] + bias ----------------
// one wave per (branch, dst); lane holds 8 contiguous channels (head = lane/16)
__global__ __launch_bounds__(256) void agg_kernel(
    const float* __restrict__ H, const float* __restrict__ ex, const float* __restrict__ den,
    const int* __restrict__ rowptr, const int* __restrict__ csr_src,
    const int* __restrict__ csr_eid,
    const float* __restrict__ b0, const float* __restrict__ b1,
    float* __restrict__ OUT, int g) {
    int z = blockIdx.y;
    int n = blockIdx.x * 4 + (threadIdx.x >> 6);
    int lane = threadIdx.x & 63;
    if (n >= NNODES) return;
    int head = lane >> 4;
    const int* rp = rowptr + g * (NNODES + 1);
    int beg = rp[n], end = rp[n + 1];
    float inv = 1.0f / den[((long)z * NNODES + n) * 4 + head];
    const int* cs = csr_src + (long)g * ETOT;
    const int* ce = csr_eid + (long)g * ETOT;
    float4 acc0 = make_float4(0.f, 0.f, 0.f, 0.f);
    float4 acc1 = make_float4(0.f, 0.f, 0.f, 0.f);
    for (int j = beg; j < end; j++) {
        int src = cs[j];
        int eid = ce[j];
        float w = ex[((long)z * ETOT + eid) * 4 + head];
        const float* hp = H + ((long)z * NNODES + src) * HC + lane * 8;
        float4 h0 = *(const float4*)hp;
        float4 h1 = *(const float4*)(hp + 4);
        acc0.x = fmaf(w, h0.x, acc0.x); acc0.y = fmaf(w, h0.y, acc0.y);
        acc0.z = fmaf(w, h0.z, acc0.z); acc0.w = fmaf(w, h0.w, acc0.w);
        acc1.x = fmaf(w, h1.x, acc1.x); acc1.y = fmaf(w, h1.y, acc1.y);
        acc1.z = fmaf(w, h1.z, acc1.z); acc1.w = fmaf(w, h1.w, acc1.w);
    }
    const float* bias = z ? b1 : b0;
    float4 bb0 = *(const float4*)&bias[lane * 8];
    float4 bb1 = *(const float4*)&bias[lane * 8 + 4];
    float* op = OUT + ((long)z * NNODES + n) * HC + lane * 8;
    float4 o0 = make_float4(acc0.x * inv + bb0.x, acc0.y * inv + bb0.y,
                            acc0.z * inv + bb0.z, acc0.w * inv + bb0.w);
    float4 o1 = make_float4(acc1.x * inv + bb1.x, acc1.y * inv + bb1.y,
                            acc1.z * inv + bb1.z, acc1.w * inv + bb1.w);
    *(float4*)op = o0;
    *(float4*)(op + 4) = o1;
}

// ---------------- gather clf_nodes into flat MLP input (reversed timestep order) ----------------
__global__ void gather_kernel(const float* __restrict__ X, const int* __restrict__ clf,
                              float* __restrict__ flat, int t) {
    int b = blockIdx.x;
    int z = blockIdx.y;
    int j = threadIdx.x;  // 128
    int node = clf[b];
    flat[(long)b * (TSTEPS * 2 * EMB) + (TSTEPS - 1 - t) * (2 * EMB) + z * EMB + j] =
        X[((long)z * NNODES + node) * EMB + j];
}

// ---------------- fc2: [B,128] @ [2,128]^T + bias, relu ----------------
__global__ void fc2_kernel(const float* __restrict__ h1, const float* __restrict__ W,
                           const float* __restrict__ bias, float* __restrict__ out) {
    int row = blockIdx.x;
    int lane = threadIdx.x;  // 64
    float x0 = h1[(long)row * 128 + lane];
    float x1 = h1[(long)row * 128 + 64 + lane];
    float p0 = x0 * W[lane] + x1 * W[64 + lane];
    float p1 = x0 * W[128 + lane] + x1 * W[192 + lane];
    for (int off = 32; off; off >>= 1) {
        p0 += __shfl_down(p0, off);
        p1 += __shfl_down(p1, off);
    }
    if (lane == 0) {
        out[row * 2 + 0] = fmaxf(p0 + bias[0], 0.f);
        out[row * 2 + 1] = fmaxf(p1 + bias[1], 0.f);
    }
}

extern "C" void kernel_launch(void* const* d_in, const int* in_sizes, int n_in,
                              void* d_out, int out_size, void* d_ws, size_t ws_size,
                              hipStream_t stream) {
    const float* emb     = (const float*)d_in[0];
    const int*   edges   = (const int*)d_in[1];
    const int*   clf     = (const int*)d_in[5];
    const float* gat_W1  = (const float*)d_in[6];
    const float* gat_as1 = (const float*)d_in[7];
    const float* gat_ad1 = (const float*)d_in[8];
    const float* gat_b1  = (const float*)d_in[9];
    const float* lin_W1  = (const float*)d_in[10];
    const float* lin_b1  = (const float*)d_in[11];
    const float* gat_W2  = (const float*)d_in[12];
    const float* gat_as2 = (const float*)d_in[13];
    const float* gat_ad2 = (const float*)d_in[14];
    const float* gat_b2  = (const float*)d_in[15];
    const float* lin_W2  = (const float*)d_in[16];
    const float* lin_b2  = (const float*)d_in[17];
    const float* fc1_W   = (const float*)d_in[18];
    const float* fc1_b   = (const float*)d_in[19];
    const float* fc2_W   = (const float*)d_in[20];
    const float* fc2_b   = (const float*)d_in[21];
    float* out = (float*)d_out;

    char* ws = (char*)d_ws;
    size_t off = 0;
    auto alloc = [&](size_t bytes) -> char* {
        char* p = ws + off;
        off += (bytes + 255) & ~(size_t)255;
        return p;
    };
    int*   counts  = (int*)alloc((size_t)TSTEPS * NNODES * 4);
    int*   cursor  = (int*)alloc((size_t)TSTEPS * NNODES * 4);
    int*   rowptr  = (int*)alloc((size_t)TSTEPS * (NNODES + 1) * 4);
    int*   csr_src = (int*)alloc((size_t)TSTEPS * ETOT * 4);
    int*   csr_eid = (int*)alloc((size_t)TSTEPS * ETOT * 4);
    float* Xbuf    = (float*)alloc((size_t)2 * NNODES * EMB * 4);
    float* Hbuf    = (float*)alloc((size_t)2 * NNODES * HC * 4);
    float* OUTbuf  = (float*)alloc((size_t)2 * NNODES * HC * 4);
    float* s_src   = (float*)alloc((size_t)2 * NNODES * 4 * 4);
    float* s_dst   = (float*)alloc((size_t)2 * NNODES * 4 * 4);
    float* den     = (float*)alloc((size_t)2 * NNODES * 4 * 4);
    float* exbuf   = (float*)alloc((size_t)2 * ETOT * 4 * 4);
    float* flat    = (float*)alloc((size_t)BCLF * (TSTEPS * 2 * EMB) * 4);
    float* h1buf   = (float*)alloc((size_t)BCLF * EMB * 4);

    const int eblocks = (ETOT + 255) / 256;  // 1329

    // CSR build for all 10 graphs (shared by branches & layers)
    hipMemsetAsync(counts, 0, (size_t)TSTEPS * NNODES * 4, stream);
    count_kernel<<<dim3(eblocks, TSTEPS), 256, 0, stream>>>(edges, counts);
    scan_kernel<<<TSTEPS, 256, 0, stream>>>(counts, rowptr, cursor);
    fill_kernel<<<dim3(eblocks, TSTEPS), 256, 0, stream>>>(edges, cursor, csr_src, csr_eid);

    for (int t = 0; t < TSTEPS; t++) {
        for (int l = 0; l < 2; l++) {
            const float* A0 = (l == 0) ? emb + (long)t * NNODES * EMB : Xbuf;
            const float* A1 = (l == 0) ? A0 : Xbuf + (long)NNODES * EMB;
            // H = X @ gat_W^T   [N,128]x[512,128]^T -> [N,512]
            gemm_tn<128, 128, 8, 8, false, false>
                <<<dim3(157, 4, 2), dim3(16, 16), 0, stream>>>(
                    A0, A1, gat_W1 + (long)l * HC * EMB, gat_W2 + (long)l * HC * EMB,
                    nullptr, nullptr, Hbuf, (long)NNODES * HC, NNODES, HC, EMB);
            scores_kernel<<<dim3(5000, 2), 256, 0, stream>>>(
                Hbuf, gat_as1 + l * HC, gat_as2 + l * HC,
                gat_ad1 + l * HC, gat_ad2 + l * HC, s_src, s_dst, den);
            edge_kernel<<<dim3(eblocks, 2), 256, 0, stream>>>(
                edges, s_src, s_dst, exbuf, den, t);
            agg_kernel<<<dim3(5000, 2), 256, 0, stream>>>(
                Hbuf, exbuf, den, rowptr, csr_src, csr_eid,
                gat_b1 + l * HC, gat_b2 + l * HC, OUTbuf, t);
            // X' = relu(OUT @ lin_W^T + lin_b)   [N,512]x[128,512]^T -> [N,128]
            gemm_tn<64, 64, 4, 4, true, true>
                <<<dim3(313, 2, 2), dim3(16, 16), 0, stream>>>(
                    OUTbuf, OUTbuf + (long)NNODES * HC,
                    lin_W1 + (long)l * EMB * HC, lin_W2 + (long)l * EMB * HC,
                    lin_b1 + l * EMB, lin_b2 + l * EMB,
                    Xbuf, (long)NNODES * EMB, NNODES, EMB, HC);
        }
        gather_kernel<<<dim3(BCLF, 2), 128, 0, stream>>>(Xbuf, clf, flat, t);
    }
    // h1 = relu(flat @ fc1_W^T + fc1_b)   [B,2560]x[128,2560]^T -> [B,128]
    gemm_tn<64, 64, 4, 4, true, true><<<dim3(64, 2, 1), dim3(16, 16), 0, stream>>>(
        flat, flat, fc1_W, fc1_W, fc1_b, fc1_b, h1buf, 0, BCLF, EMB, TSTEPS * 2 * EMB);
    fc2_kernel<<<BCLF, 64, 0, stream>>>(h1buf, fc2_W, fc2_b, out);
}

// Round 3
// 4685.031 us; speedup vs baseline: 2.3427x; 2.3427x over previous
//
#include <hip/hip_runtime.h>
#include <cstdint>

#define NNODES 20000
#define NEDGES 320000
#define ETOT   340000   // NEDGES + NNODES self loops
#define TSTEPS 10
#define BCLF   4096
#define EMB    128
#define HC     512      // HEADS * EMB
#define NEG_SLOPE 0.2f

typedef __attribute__((ext_vector_type(8))) short short8;
typedef __attribute__((ext_vector_type(4))) float floatx4;

__device__ __forceinline__ unsigned short f2bf(float f) {
    unsigned int u = __float_as_uint(f);
    u += 0x7fffu + ((u >> 16) & 1u);   // RNE
    return (unsigned short)(u >> 16);
}
__device__ __forceinline__ float bf2f(unsigned short s) {
    return __uint_as_float(((unsigned int)s) << 16);
}

// ---------------- f32 -> (hi, lo) bf16 split (4 elems/thread) ----------------
__global__ void cvt_split_kernel(const float* __restrict__ in,
                                 unsigned short* __restrict__ hi,
                                 unsigned short* __restrict__ lo, long n4) {
    long i = (long)blockIdx.x * 256 + threadIdx.x;
    if (i >= n4) return;
    float4 v = *(const float4*)&in[i * 4];
    ushort4 h, l;
    h.x = f2bf(v.x); l.x = f2bf(v.x - bf2f(h.x));
    h.y = f2bf(v.y); l.y = f2bf(v.y - bf2f(h.y));
    h.z = f2bf(v.z); l.z = f2bf(v.z - bf2f(h.z));
    h.w = f2bf(v.w); l.w = f2bf(v.w - bf2f(h.w));
    *(ushort4*)&hi[i * 4] = h;
    *(ushort4*)&lo[i * 4] = l;
}

// ---------------- CSR build (once for all 10 graphs) ----------------
__global__ void count_kernel(const int* __restrict__ edges, int* __restrict__ counts) {
    int e = blockIdx.x * 256 + threadIdx.x;
    int g = blockIdx.y;
    if (e >= ETOT) return;
    int d = (e < NEDGES) ? edges[(g * 2 + 1) * NEDGES + e] : (e - NEDGES);
    atomicAdd(&counts[g * NNODES + d], 1);
}

__global__ void scan_kernel(const int* __restrict__ counts, int* __restrict__ rowptr,
                            int* __restrict__ cursor) {
    int g = blockIdx.x;
    __shared__ int buf[256];
    __shared__ int carry_s;
    if (threadIdx.x == 0) carry_s = 0;
    __syncthreads();
    const int* c = counts + g * NNODES;
    int* rp = rowptr + g * (NNODES + 1);
    int* cu = cursor + g * NNODES;
    for (int base = 0; base < NNODES; base += 256) {
        int i = base + threadIdx.x;
        int v = (i < NNODES) ? c[i] : 0;
        buf[threadIdx.x] = v;
        __syncthreads();
        for (int off = 1; off < 256; off <<= 1) {
            int t = (threadIdx.x >= off) ? buf[threadIdx.x - off] : 0;
            __syncthreads();
            buf[threadIdx.x] += t;
            __syncthreads();
        }
        int excl = carry_s + buf[threadIdx.x] - v;
        if (i < NNODES) { rp[i] = excl; cu[i] = excl; }
        int tot = buf[255];
        __syncthreads();
        if (threadIdx.x == 0) carry_s += tot;
        __syncthreads();
    }
    if (threadIdx.x == 0) rp[NNODES] = carry_s;
}

__global__ void fill_kernel(const int* __restrict__ edges, int* __restrict__ cursor,
                            int* __restrict__ csr_src) {
    int e = blockIdx.x * 256 + threadIdx.x;
    int g = blockIdx.y;
    if (e >= ETOT) return;
    int s, d;
    if (e < NEDGES) { s = edges[(g * 2) * NEDGES + e]; d = edges[(g * 2 + 1) * NEDGES + e]; }
    else           { s = e - NEDGES; d = s; }
    int pos = atomicAdd(&cursor[g * NNODES + d], 1);
    csr_src[(long)g * ETOT + pos] = s;
}

// ---------------- precompute was/wad: was[l][z][h][k] = sum_c W[h*128+c][k]*as[h][c] ----------------
__global__ void prep_was_kernel(const float* __restrict__ W1, const float* __restrict__ W2,
                                const float* __restrict__ as1, const float* __restrict__ as2,
                                const float* __restrict__ ad1, const float* __restrict__ ad2,
                                float* __restrict__ was, float* __restrict__ wad) {
    int b = blockIdx.x;            // l*8 + z*4 + h
    int l = b >> 3, z = (b >> 2) & 1, h = b & 3;
    int k = threadIdx.x;           // 128
    const float* W  = z ? W2 : W1;
    const float* av = z ? as2 : as1;
    const float* dv = z ? ad2 : ad1;
    float s = 0.f, d = 0.f;
    for (int c = 0; c < 128; c++) {
        float w = W[(long)l * HC * EMB + (h * 128 + c) * 128 + k];
        s = fmaf(w, av[(l * 4 + h) * 128 + c], s);
        d = fmaf(w, dv[(l * 4 + h) * 128 + c], d);
    }
    long idx = ((l * 2 + z) * 4 + h) * 128 + k;
    was[idx] = s;
    wad[idx] = d;
}

// ---------------- split-bf16 MFMA GEMM: C = op(A @ B^T + bias) ----------------
// A = Ah+Al, B = Bh+Bl (hi/lo bf16 pairs). 3 MFMAs per product term (hh+hl+lh) ~ fp32.
// Tile 128x128, BK=32, 4 waves, 4x4 of 16x16x32 MFMAs per wave.
// OMODE: 0 = fp32 out (Cf), 1 = bf16 out (Chi), 2 = split out (Chi+Clo).
template <bool RELU, bool BIAS, int OMODE>
__global__ __launch_bounds__(256) void gemm_split(
    const unsigned short* __restrict__ A0h, const unsigned short* __restrict__ A0l,
    const unsigned short* __restrict__ A1h, const unsigned short* __restrict__ A1l,
    const unsigned short* __restrict__ B0h, const unsigned short* __restrict__ B0l,
    const unsigned short* __restrict__ B1h, const unsigned short* __restrict__ B1l,
    const float* __restrict__ bias0, const float* __restrict__ bias1,
    float* __restrict__ Cf, unsigned short* __restrict__ Chi, unsigned short* __restrict__ Clo,
    long cStride, int M, int N, int K) {
    const int z = blockIdx.z;
    const unsigned short* __restrict__ Ah = z ? A1h : A0h;
    const unsigned short* __restrict__ Al = z ? A1l : A0l;
    const unsigned short* __restrict__ Bh = z ? B1h : B0h;
    const unsigned short* __restrict__ Bl = z ? B1l : B0l;
    const float* __restrict__ bias = z ? bias1 : bias0;

    __shared__ short As[2][4 * 128 * 8];   // [hi/lo] 8 KB each
    __shared__ short Bs[2][4 * 128 * 8];

    const int tid = threadIdx.x;
    const int row0 = blockIdx.x * 128;
    const int col0 = blockIdx.y * 128;

    const int wave = tid >> 6;
    const int lane = tid & 63;
    const int wm = (wave >> 1) * 64;
    const int wn = (wave & 1) * 64;
    const int chunk = lane >> 4;
    const int l16 = lane & 15;

    floatx4 acc[4][4];
#pragma unroll
    for (int i = 0; i < 4; i++)
#pragma unroll
        for (int j = 0; j < 4; j++) acc[i][j] = (floatx4)0.0f;

    for (int k0 = 0; k0 < K; k0 += 32) {
        __syncthreads();
#pragma unroll
        for (int p = 0; p < 2; p++) {
            int idx = p * 256 + tid;
            int r = idx >> 2, kc = idx & 3;
            int arow = row0 + r;
            short8 vah = (short8)0, val = (short8)0;
            if (arow < M) {
                vah = *(const short8*)&Ah[(long)arow * K + k0 + kc * 8];
                val = *(const short8*)&Al[(long)arow * K + k0 + kc * 8];
            }
            *(short8*)&As[0][(kc * 128 + r) * 8] = vah;
            *(short8*)&As[1][(kc * 128 + r) * 8] = val;
            long boff = (long)(col0 + r) * K + k0 + kc * 8;
            *(short8*)&Bs[0][(kc * 128 + r) * 8] = *(const short8*)&Bh[boff];
            *(short8*)&Bs[1][(kc * 128 + r) * 8] = *(const short8*)&Bl[boff];
        }
        __syncthreads();
        short8 afh[4], afl[4], bfh[4], bfl[4];
#pragma unroll
        for (int mi = 0; mi < 4; mi++) {
            int o = (chunk * 128 + wm + mi * 16 + l16) * 8;
            afh[mi] = *(const short8*)&As[0][o];
            afl[mi] = *(const short8*)&As[1][o];
        }
#pragma unroll
        for (int ni = 0; ni < 4; ni++) {
            int o = (chunk * 128 + wn + ni * 16 + l16) * 8;
            bfh[ni] = *(const short8*)&Bs[0][o];
            bfl[ni] = *(const short8*)&Bs[1][o];
        }
#pragma unroll
        for (int mi = 0; mi < 4; mi++)
#pragma unroll
            for (int ni = 0; ni < 4; ni++) {
                acc[mi][ni] = __builtin_amdgcn_mfma_f32_16x16x32_bf16(
                    afh[mi], bfh[ni], acc[mi][ni], 0, 0, 0);
                acc[mi][ni] = __builtin_amdgcn_mfma_f32_16x16x32_bf16(
                    afh[mi], bfl[ni], acc[mi][ni], 0, 0, 0);
                acc[mi][ni] = __builtin_amdgcn_mfma_f32_16x16x32_bf16(
                    afl[mi], bfh[ni], acc[mi][ni], 0, 0, 0);
            }
    }

    // C/D layout: col = lane&15, row = (lane>>4)*4 + reg
    const int r4 = (lane >> 4) * 4;
#pragma unroll
    for (int mi = 0; mi < 4; mi++) {
#pragma unroll
        for (int reg = 0; reg < 4; reg++) {
            int row = row0 + wm + mi * 16 + r4 + reg;
            if (row >= M) continue;
#pragma unroll
            for (int ni = 0; ni < 4; ni++) {
                int col = col0 + wn + ni * 16 + l16;
                float v = acc[mi][ni][reg];
                if (BIAS) v += bias[col];
                if (RELU) v = fmaxf(v, 0.f);
                long o = (long)z * cStride + (long)row * N + col;
                if (OMODE == 0) {
                    Cf[o] = v;
                } else if (OMODE == 1) {
                    Chi[o] = f2bf(v);
                } else {
                    unsigned short h = f2bf(v);
                    Chi[o] = h;
                    Clo[o] = f2bf(v - bf2f(h));
                }
            }
        }
    }
}

// ---------------- attention scores from X: s = X @ was^T ----------------
// one wave per (branch, node); lane covers k and k+64
__global__ __launch_bounds__(256) void scores_x_kernel(
    const unsigned short* __restrict__ X0h, const unsigned short* __restrict__ X0l,
    const unsigned short* __restrict__ X1h, const unsigned short* __restrict__ X1l,
    const float* __restrict__ was, const float* __restrict__ wad,  // [z][4][128] for this layer
    float* __restrict__ s_src, float* __restrict__ s_dst) {
    int z = blockIdx.y;
    int n = blockIdx.x * 4 + (threadIdx.x >> 6);
    int lane = threadIdx.x & 63;
    if (n >= NNODES) return;
    const unsigned short* Xh = z ? X1h : X0h;
    const unsigned short* Xl = z ? X1l : X0l;
    float x0 = bf2f(Xh[(long)n * 128 + lane]) + bf2f(Xl[(long)n * 128 + lane]);
    float x1 = bf2f(Xh[(long)n * 128 + 64 + lane]) + bf2f(Xl[(long)n * 128 + 64 + lane]);
    const float* wz = was + z * 512;
    const float* dz = wad + z * 512;
    float ps[4], pd[4];
#pragma unroll
    for (int h = 0; h < 4; h++) {
        ps[h] = x0 * wz[h * 128 + lane] + x1 * wz[h * 128 + 64 + lane];
        pd[h] = x0 * dz[h * 128 + lane] + x1 * dz[h * 128 + 64 + lane];
    }
    for (int off = 32; off; off >>= 1) {
#pragma unroll
        for (int h = 0; h < 4; h++) {
            ps[h] += __shfl_down(ps[h], off);
            pd[h] += __shfl_down(pd[h], off);
        }
    }
    if (lane == 0) {
        long idx = ((long)z * NNODES + n) * 4;
#pragma unroll
        for (int h = 0; h < 4; h++) {
            s_src[idx + h] = ps[h];
            s_dst[idx + h] = pd[h];
        }
    }
}

// ---------------- CSR aggregation: den in-register, bf16 H gather, split OUT ----------------
// one wave per (branch, dst); lane holds 8 contiguous channels (head = lane/16)
__global__ __launch_bounds__(256) void agg_kernel(
    const unsigned short* __restrict__ H,
    const float* __restrict__ s_src, const float* __restrict__ s_dst,
    const int* __restrict__ rowptr, const int* __restrict__ csr_src,
    const float* __restrict__ b0, const float* __restrict__ b1,
    unsigned short* __restrict__ OUTh, unsigned short* __restrict__ OUTl, int g) {
    int z = blockIdx.y;
    int n = blockIdx.x * 4 + (threadIdx.x >> 6);
    int lane = threadIdx.x & 63;
    if (n >= NNODES) return;
    int head = lane >> 4;
    const int* rp = rowptr + g * (NNODES + 1);
    int beg = rp[n], end = rp[n + 1];
    float sd = s_dst[((long)z * NNODES + n) * 4 + head];
    const int* cs = csr_src + (long)g * ETOT;
    float acc[8];
#pragma unroll
    for (int c = 0; c < 8; c++) acc[c] = 0.f;
    float den = 0.f;
    for (int j = beg; j < end; j++) {
        int src = cs[j];
        float ss = s_src[((long)z * NNODES + src) * 4 + head];
        float l = ss + sd;
        l = (l >= 0.f) ? l : NEG_SLOPE * l;
        float w = __expf(l);
        den += w;
        short8 h = *(const short8*)&H[((long)z * NNODES + src) * HC + lane * 8];
#pragma unroll
        for (int c = 0; c < 8; c++) acc[c] = fmaf(w, bf2f((unsigned short)h[c]), acc[c]);
    }
    float inv = 1.0f / den;
    const float* bias = z ? b1 : b0;
    short8 oh, ol;
#pragma unroll
    for (int c = 0; c < 8; c++) {
        float v = acc[c] * inv + bias[lane * 8 + c];
        unsigned short hbits = f2bf(v);
        oh[c] = (short)hbits;
        ol[c] = (short)f2bf(v - bf2f(hbits));
    }
    long o = ((long)z * NNODES + n) * HC + lane * 8;
    *(short8*)&OUTh[o] = oh;
    *(short8*)&OUTl[o] = ol;
}

// ---------------- gather clf_nodes into flat MLP input (reversed timesteps) ----------------
__global__ void gather_kernel(const unsigned short* __restrict__ Xh,
                              const unsigned short* __restrict__ Xl,
                              const int* __restrict__ clf,
                              unsigned short* __restrict__ flath,
                              unsigned short* __restrict__ flatl, int t) {
    int b = blockIdx.x;
    int z = blockIdx.y;
    int j = threadIdx.x;  // 64 uints = 128 bf16
    int node = clf[b];
    long dst = (long)b * (TSTEPS * 2 * EMB) + (TSTEPS - 1 - t) * (2 * EMB) + z * EMB;
    long src = ((long)z * NNODES + node) * EMB;
    ((unsigned int*)&flath[dst])[j] = ((const unsigned int*)&Xh[src])[j];
    ((unsigned int*)&flatl[dst])[j] = ((const unsigned int*)&Xl[src])[j];
}

// ---------------- fc2: [B,128] @ [2,128]^T + bias, relu, fp32 out ----------------
__global__ void fc2_kernel(const float* __restrict__ h1, const float* __restrict__ W,
                           const float* __restrict__ bias, float* __restrict__ out) {
    int row = blockIdx.x;
    int lane = threadIdx.x;  // 64
    float x0 = h1[(long)row * 128 + lane];
    float x1 = h1[(long)row * 128 + 64 + lane];
    float p0 = x0 * W[lane] + x1 * W[64 + lane];
    float p1 = x0 * W[128 + lane] + x1 * W[192 + lane];
    for (int off = 32; off; off >>= 1) {
        p0 += __shfl_down(p0, off);
        p1 += __shfl_down(p1, off);
    }
    if (lane == 0) {
        out[row * 2 + 0] = fmaxf(p0 + bias[0], 0.f);
        out[row * 2 + 1] = fmaxf(p1 + bias[1], 0.f);
    }
}

extern "C" void kernel_launch(void* const* d_in, const int* in_sizes, int n_in,
                              void* d_out, int out_size, void* d_ws, size_t ws_size,
                              hipStream_t stream) {
    const float* emb     = (const float*)d_in[0];
    const int*   edges   = (const int*)d_in[1];
    const int*   clf     = (const int*)d_in[5];
    const float* gat_W1  = (const float*)d_in[6];
    const float* gat_as1 = (const float*)d_in[7];
    const float* gat_ad1 = (const float*)d_in[8];
    const float* gat_b1  = (const float*)d_in[9];
    const float* lin_W1  = (const float*)d_in[10];
    const float* lin_b1  = (const float*)d_in[11];
    const float* gat_W2  = (const float*)d_in[12];
    const float* gat_as2 = (const float*)d_in[13];
    const float* gat_ad2 = (const float*)d_in[14];
    const float* gat_b2  = (const float*)d_in[15];
    const float* lin_W2  = (const float*)d_in[16];
    const float* lin_b2  = (const float*)d_in[17];
    const float* fc1_W   = (const float*)d_in[18];
    const float* fc1_b   = (const float*)d_in[19];
    const float* fc2_W   = (const float*)d_in[20];
    const float* fc2_b   = (const float*)d_in[21];
    float* out = (float*)d_out;

    char* ws = (char*)d_ws;
    size_t off = 0;
    auto alloc = [&](size_t bytes) -> char* {
        char* p = ws + off;
        off += (bytes + 255) & ~(size_t)255;
        return p;
    };
    int* counts  = (int*)alloc((size_t)TSTEPS * NNODES * 4);
    int* cursor  = (int*)alloc((size_t)TSTEPS * NNODES * 4);
    int* rowptr  = (int*)alloc((size_t)TSTEPS * (NNODES + 1) * 4);
    int* csr_src = (int*)alloc((size_t)TSTEPS * ETOT * 4);
    unsigned short* emb_hi = (unsigned short*)alloc((size_t)TSTEPS * NNODES * EMB * 2);
    unsigned short* emb_lo = (unsigned short*)alloc((size_t)TSTEPS * NNODES * EMB * 2);
    unsigned short* gW1h = (unsigned short*)alloc((size_t)2 * HC * EMB * 2);
    unsigned short* gW1l = (unsigned short*)alloc((size_t)2 * HC * EMB * 2);
    unsigned short* gW2h = (unsigned short*)alloc((size_t)2 * HC * EMB * 2);
    unsigned short* gW2l = (unsigned short*)alloc((size_t)2 * HC * EMB * 2);
    unsigned short* lW1h = (unsigned short*)alloc((size_t)2 * EMB * HC * 2);
    unsigned short* lW1l = (unsigned short*)alloc((size_t)2 * EMB * HC * 2);
    unsigned short* lW2h = (unsigned short*)alloc((size_t)2 * EMB * HC * 2);
    unsigned short* lW2l = (unsigned short*)alloc((size_t)2 * EMB * HC * 2);
    unsigned short* fc1Wh = (unsigned short*)alloc((size_t)EMB * 2 * EMB * TSTEPS * 2);
    unsigned short* fc1Wl = (unsigned short*)alloc((size_t)EMB * 2 * EMB * TSTEPS * 2);
    float* wasb = (float*)alloc((size_t)2 * 2 * 4 * 128 * 4);
    float* wadb = (float*)alloc((size_t)2 * 2 * 4 * 128 * 4);
    unsigned short* Xh   = (unsigned short*)alloc((size_t)2 * NNODES * EMB * 2);
    unsigned short* Xl   = (unsigned short*)alloc((size_t)2 * NNODES * EMB * 2);
    unsigned short* Hbf  = (unsigned short*)alloc((size_t)2 * NNODES * HC * 2);
    unsigned short* OUTh = (unsigned short*)alloc((size_t)2 * NNODES * HC * 2);
    unsigned short* OUTl = (unsigned short*)alloc((size_t)2 * NNODES * HC * 2);
    float* s_src = (float*)alloc((size_t)2 * NNODES * 4 * 4);
    float* s_dst = (float*)alloc((size_t)2 * NNODES * 4 * 4);
    unsigned short* flath = (unsigned short*)alloc((size_t)BCLF * (TSTEPS * 2 * EMB) * 2);
    unsigned short* flatl = (unsigned short*)alloc((size_t)BCLF * (TSTEPS * 2 * EMB) * 2);
    float* h1buf = (float*)alloc((size_t)BCLF * EMB * 4);

    const int eblocks = (ETOT + 255) / 256;  // 1329

    // f32 -> bf16 hi/lo splits (once per launch)
    {
        long n4 = (long)TSTEPS * NNODES * EMB / 4;
        cvt_split_kernel<<<(int)((n4 + 255) / 256), 256, 0, stream>>>(emb, emb_hi, emb_lo, n4);
        long w4 = (long)2 * HC * EMB / 4;
        int wb = (int)((w4 + 255) / 256);
        cvt_split_kernel<<<wb, 256, 0, stream>>>(gat_W1, gW1h, gW1l, w4);
        cvt_split_kernel<<<wb, 256, 0, stream>>>(gat_W2, gW2h, gW2l, w4);
        cvt_split_kernel<<<wb, 256, 0, stream>>>(lin_W1, lW1h, lW1l, w4);
        cvt_split_kernel<<<wb, 256, 0, stream>>>(lin_W2, lW2h, lW2l, w4);
        long f4 = (long)EMB * 2 * EMB * TSTEPS / 4;
        cvt_split_kernel<<<(int)((f4 + 255) / 256), 256, 0, stream>>>(fc1_W, fc1Wh, fc1Wl, f4);
    }
    prep_was_kernel<<<16, 128, 0, stream>>>(gat_W1, gat_W2, gat_as1, gat_as2,
                                            gat_ad1, gat_ad2, wasb, wadb);

    // CSR build for all 10 graphs (shared by branches & layers)
    hipMemsetAsync(counts, 0, (size_t)TSTEPS * NNODES * 4, stream);
    count_kernel<<<dim3(eblocks, TSTEPS), 256, 0, stream>>>(edges, counts);
    scan_kernel<<<TSTEPS, 256, 0, stream>>>(counts, rowptr, cursor);
    fill_kernel<<<dim3(eblocks, TSTEPS), 256, 0, stream>>>(edges, cursor, csr_src);

    for (int t = 0; t < TSTEPS; t++) {
        for (int l = 0; l < 2; l++) {
            const unsigned short* A0h = (l == 0) ? emb_hi + (long)t * NNODES * EMB : Xh;
            const unsigned short* A0l = (l == 0) ? emb_lo + (long)t * NNODES * EMB : Xl;
            const unsigned short* A1h = (l == 0) ? A0h : Xh + (long)NNODES * EMB;
            const unsigned short* A1l = (l == 0) ? A0l : Xl + (long)NNODES * EMB;
            // scores from X (independent of H)
            scores_x_kernel<<<dim3(5000, 2), 256, 0, stream>>>(
                A0h, A0l, A1h, A1l, wasb + l * 1024, wadb + l * 1024, s_src, s_dst);
            // H = X @ gat_W^T  [N,128]x[512,128]^T -> [N,512], bf16 out
            gemm_split<false, false, 1><<<dim3(157, 4, 2), 256, 0, stream>>>(
                A0h, A0l, A1h, A1l,
                gW1h + (long)l * HC * EMB, gW1l + (long)l * HC * EMB,
                gW2h + (long)l * HC * EMB, gW2l + (long)l * HC * EMB,
                nullptr, nullptr, nullptr, Hbf, nullptr,
                (long)NNODES * HC, NNODES, HC, EMB);
            // aggregation (den in-register) -> OUT hi/lo (+gat bias)
            agg_kernel<<<dim3(5000, 2), 256, 0, stream>>>(
                Hbf, s_src, s_dst, rowptr, csr_src,
                gat_b1 + l * HC, gat_b2 + l * HC, OUTh, OUTl, t);
            // X' = relu(OUT @ lin_W^T + lin_b) -> split hi/lo
            gemm_split<true, true, 2><<<dim3(157, 1, 2), 256, 0, stream>>>(
                OUTh, OUTl, OUTh + (long)NNODES * HC, OUTl + (long)NNODES * HC,
                lW1h + (long)l * EMB * HC, lW1l + (long)l * EMB * HC,
                lW2h + (long)l * EMB * HC, lW2l + (long)l * EMB * HC,
                lin_b1 + l * EMB, lin_b2 + l * EMB,
                nullptr, Xh, Xl, (long)NNODES * EMB, NNODES, EMB, HC);
        }
        gather_kernel<<<dim3(BCLF, 2), 64, 0, stream>>>(Xh, Xl, clf, flath, flatl, t);
    }
    // h1 = relu(flat @ fc1_W^T + fc1_b)  [B,2560]x[128,2560]^T -> [B,128] fp32
    gemm_split<true, true, 0><<<dim3(32, 1, 1), 256, 0, stream>>>(
        flath, flatl, flath, flatl, fc1Wh, fc1Wl, fc1Wh, fc1Wl,
        fc1_b, fc1_b, h1buf, nullptr, nullptr, 0, BCLF, EMB, TSTEPS * 2 * EMB);
    fc2_kernel<<<BCLF, 64, 0, stream>>>(h1buf, fc2_W, fc2_b, out);
}